// Round 1
// baseline (523.565 us; speedup 1.0000x reference)
//
#include <hip/hip_runtime.h>
#include <cstdint>

#define CC 32
#define DD 9
#define CD 288   // C*D
#define BB 8
#define HH 64
#define ZZ 4

__device__ __forceinline__ float silu_f(float v) {
  return v / (1.0f + __expf(-v));
}

__device__ __forceinline__ int blk_of(int d) { return d == 0 ? 0 : (d < 4 ? 1 : 2); }

__global__ __launch_bounds__(256) void k_zero(float* __restrict__ p, int n) {
  int i = blockIdx.x * 256 + threadIdx.x;
  if (i < n) p[i] = 0.0f;
}

// x[n][d][q] = sum_c nf[n][c][d] * Wup[l(d)][c][q]   (note transposed [N][9][32] output)
__global__ __launch_bounds__(256) void k_linear_up(
    const float* __restrict__ nf, const float* __restrict__ Wup,
    float* __restrict__ x, int N) {
  __shared__ float sW[3 * CC * CC];   // 3072
  __shared__ float snf[8 * CD];       // 2304
  for (int i = threadIdx.x; i < 3 * CC * CC; i += 256) sW[i] = Wup[i];
  int node0 = blockIdx.x * 8;
  int cnt = N - node0; if (cnt > 8) cnt = 8;
  const float* src = nf + (size_t)node0 * CD;
  for (int i = threadIdx.x; i < cnt * CD; i += 256) snf[i] = src[i];
  __syncthreads();
  float* dst = x + (size_t)node0 * CD;
  for (int o = threadIdx.x; o < cnt * CD; o += 256) {
    int nl = o / CD, rem = o - nl * CD;
    int d = rem >> 5, q = rem & 31;
    int l = blk_of(d);
    const float* wcol = sW + l * (CC * CC) + q;   // + c*32
    const float* frow = snf + nl * CD + d;        // + c*9
    float acc = 0.f;
#pragma unroll
    for (int c = 0; c < CC; ++c) acc += frow[c * DD] * wcol[c * CC];
    dst[o] = acc;
  }
}

// fused radial MLP + weighted TP + atomic scatter.
// block = 256 = 8 edges x 32 channel-lanes
__global__ __launch_bounds__(256) void k_edge(
    const float* __restrict__ ef, const float* __restrict__ esh,
    const float* __restrict__ cut,
    const float* __restrict__ W1, const float* __restrict__ W2,
    const float* __restrict__ W3, const float* __restrict__ CG,
    const float* __restrict__ x,
    const int* __restrict__ esrc, const int* __restrict__ edst,
    float* __restrict__ mpre, int E) {
  __shared__ float sW1[BB * HH];        // 512
  __shared__ float sW2[HH * HH];        // 4096
  __shared__ float sW3[HH * CC];        // 2048
  __shared__ float sCG[DD * DD * DD];   // 729
  __shared__ float sh1[8][HH];
  __shared__ float sh2[8][HH];
  __shared__ float sR[8][81];
  __shared__ float sef[64];
  __shared__ float ssh[72];
  __shared__ float scut[8];
  __shared__ int   ssrc[8];
  __shared__ int   sdst[8];

  for (int i = threadIdx.x; i < BB * HH; i += 256) sW1[i] = W1[i];
  for (int i = threadIdx.x; i < HH * HH; i += 256) sW2[i] = W2[i];
  for (int i = threadIdx.x; i < HH * CC; i += 256) sW3[i] = W3[i];
  for (int i = threadIdx.x; i < DD * DD * DD; i += 256) sCG[i] = CG[i];

  int g = threadIdx.x >> 5;
  int lane = threadIdx.x & 31;
  int nbatch = E >> 3;
  for (int batch = blockIdx.x; batch < nbatch; batch += gridDim.x) {
    __syncthreads();  // also covers first-iter weight staging, prev-iter sR reads
    int t = threadIdx.x;
    if (t < 64)       sef[t]        = ef  [(size_t)batch * 64 + t];
    else if (t < 136) ssh[t - 64]   = esh [(size_t)batch * 72 + (t - 64)];
    else if (t < 144) scut[t - 136] = cut [batch * 8 + (t - 136)];
    else if (t < 152) ssrc[t - 144] = esrc[batch * 8 + (t - 144)];
    else if (t < 160) sdst[t - 152] = edst[batch * 8 + (t - 152)];
    __syncthreads();
    // layer 1: [8] -> [64], silu
#pragma unroll
    for (int half = 0; half < 2; ++half) {
      int q = lane + half * 32;
      float acc = 0.f;
#pragma unroll
      for (int k = 0; k < BB; ++k) acc += sef[g * 8 + k] * sW1[k * HH + q];
      sh1[g][q] = silu_f(acc);
    }
    __syncthreads();
    // layer 2: [64] -> [64], silu
#pragma unroll
    for (int half = 0; half < 2; ++half) {
      int q = lane + half * 32;
      float acc = 0.f;
#pragma unroll
      for (int k = 0; k < HH; ++k) acc += sh1[g][k] * sW2[k * HH + q];
      sh2[g][q] = silu_f(acc);
    }
    __syncthreads();
    // per-channel weight w_c and R[i][k] = sum_j sh[j]*CG[i][j][k]
    float wc = 0.f;
#pragma unroll
    for (int k = 0; k < HH; ++k) wc += sh2[g][k] * sW3[k * CC + lane];
    wc *= scut[g];
    for (int m = lane; m < 81; m += 32) {
      int i = m / 9, kk = m - i * 9;
      float acc = 0.f;
#pragma unroll
      for (int j = 0; j < DD; ++j) acc += ssh[g * 9 + j] * sCG[i * 81 + j * 9 + kk];
      sR[g][m] = acc;
    }
    __syncthreads();
    // TP + scatter: m_ij[c,k] = wc * sum_i xs[i][c]*R[i][k]
    {
      const float* xp = x + (size_t)ssrc[g] * CD + lane;   // [src][i][c] layout
      float xs[DD];
#pragma unroll
      for (int i = 0; i < DD; ++i) xs[i] = xp[i * 32];
      float* mp = mpre + (size_t)sdst[g] * CD + lane;      // [dst][k][c] layout
#pragma unroll
      for (int kk = 0; kk < DD; ++kk) {
        float acc = 0.f;
#pragma unroll
        for (int i = 0; i < DD; ++i) acc += xs[i] * sR[g][i * 9 + kk];
        atomicAdd(mp + kk * 32, wc * acc);
      }
    }
  }
}

// per node: m_i = block_linear(mpre, Wlin)/16 -> out1 ; W_node = attrs@Wsc ;
// scs = einsum(m_i, W_node) -> out2 (overwrites the mpre accumulator region)
__global__ __launch_bounds__(256) void k_out(
    const float* __restrict__ attrs, const float* __restrict__ Wlin,
    const float* __restrict__ Wsc,
    float* __restrict__ out1, float* __restrict__ out2, int N) {
  __shared__ float sWlin[3 * CC * CC];     // 3072
  __shared__ float sWsc[ZZ * 3 * CC * CC]; // 12288
  __shared__ float sWn[3 * CC * CC];       // 3072
  __shared__ float smp[DD * 33];           // padded [9][33]
  __shared__ float smi[DD * 33];
  for (int i = threadIdx.x; i < 3 * CC * CC; i += 256) sWlin[i] = Wlin[i];
  for (int i = threadIdx.x; i < ZZ * 3 * CC * CC; i += 256) sWsc[i] = Wsc[i];
  for (int n = blockIdx.x; n < N; n += gridDim.x) {
    __syncthreads();  // covers weight staging + prev-iter smi/sWn reads
    const float* mg = out2 + (size_t)n * CD;   // mpre [n][d][c]
    for (int j = threadIdx.x; j < CD; j += 256) {
      int dd = j >> 5, ccc = j & 31;
      smp[dd * 33 + ccc] = mg[j];
    }
    __syncthreads();
    // m_i[q][d] = (1/16) sum_c mpre[d][c] * Wlin[l][c][q]
    for (int o = threadIdx.x; o < CD; o += 256) {
      int q = o / 9, d = o - q * 9;
      int l = blk_of(d);
      float acc = 0.f;
#pragma unroll
      for (int c = 0; c < CC; ++c) acc += smp[d * 33 + c] * sWlin[l * 1024 + c * 32 + q];
      acc *= (1.0f / 16.0f);
      smi[d * 33 + q] = acc;
      out1[(size_t)n * CD + o] = acc;
    }
    // W_node[l][c][q] = sum_z attrs[n][z] * Wsc[z][l][c][q]
    float a0 = attrs[n * 4 + 0], a1 = attrs[n * 4 + 1];
    float a2 = attrs[n * 4 + 2], a3 = attrs[n * 4 + 3];
    for (int o = threadIdx.x; o < 3 * CC * CC; o += 256) {
      sWn[o] = a0 * sWsc[o] + a1 * sWsc[3072 + o] + a2 * sWsc[2 * 3072 + o] + a3 * sWsc[3 * 3072 + o];
    }
    __syncthreads();
    // scs[q][d] = sum_c m_i[c][d] * W_node[l][c][q]
    for (int o = threadIdx.x; o < CD; o += 256) {
      int q = o / 9, d = o - q * 9;
      int l = blk_of(d);
      float acc = 0.f;
#pragma unroll
      for (int c = 0; c < CC; ++c) acc += smi[d * 33 + c] * sWn[l * 1024 + c * 32 + q];
      out2[(size_t)n * CD + o] = acc;
    }
  }
}

extern "C" void kernel_launch(void* const* d_in, const int* in_sizes, int n_in,
                              void* d_out, int out_size, void* d_ws, size_t ws_size,
                              hipStream_t stream) {
  const float* nf    = (const float*)d_in[0];
  const float* attrs = (const float*)d_in[1];
  const float* ef    = (const float*)d_in[2];
  const float* esh   = (const float*)d_in[3];
  const float* cutv  = (const float*)d_in[4];
  const float* Wup   = (const float*)d_in[5];
  const float* W1    = (const float*)d_in[6];
  const float* W2    = (const float*)d_in[7];
  const float* W3    = (const float*)d_in[8];
  const float* Wlin  = (const float*)d_in[9];
  const float* Wsc   = (const float*)d_in[10];
  const float* CG    = (const float*)d_in[11];
  const int* esrc    = (const int*)d_in[12];
  const int* edst    = (const int*)d_in[13];
  int N = in_sizes[0] / CD;
  int E = in_sizes[12];
  float* out1 = (float*)d_out;
  float* out2 = out1 + (size_t)N * CD;   // doubles as the m_pre accumulator
  float* x = (float*)d_ws;               // [N][9][32] f32 = 18.9 MB

  int zn = N * CD;
  k_zero<<<(zn + 255) / 256, 256, 0, stream>>>(out2, zn);
  k_linear_up<<<(N + 7) / 8, 256, 0, stream>>>(nf, Wup, x, N);
  k_edge<<<2048, 256, 0, stream>>>(ef, esh, cutv, W1, W2, W3, CG, x, esrc, edst, out2, E);
  k_out<<<2048, 256, 0, stream>>>(attrs, Wlin, Wsc, out1, out2, N);
}

// Round 2
// 484.609 us; speedup vs baseline: 1.0804x; 1.0804x over previous
//
#include <hip/hip_runtime.h>
#include <cstdint>

#define CC 32
#define DD 9
#define CD 288   // C*D
#define BB 8
#define HH 64
#define ZZ 4

__device__ __forceinline__ float silu_f(float v) {
  return v / (1.0f + __expf(-v));
}

__device__ __forceinline__ int blk_of(int d) { return d == 0 ? 0 : (d < 4 ? 1 : 2); }

__global__ __launch_bounds__(256) void k_zero(float* __restrict__ p, int n) {
  int i = blockIdx.x * 256 + threadIdx.x;
  if (i < n) p[i] = 0.0f;
}

// ---------------- CSR build ----------------
__global__ __launch_bounds__(256) void k_hist(const int* __restrict__ edst,
                                              int* __restrict__ deg, int E) {
  int e = blockIdx.x * 256 + threadIdx.x;
  if (e < E) atomicAdd(&deg[edst[e]], 1);
}

// single block; exclusive scan of deg[N] -> offs[N+1], cursor[N]=offs[N-part]
__global__ __launch_bounds__(256) void k_scan(const int* __restrict__ deg,
                                              int* __restrict__ offs,
                                              int* __restrict__ cursor, int N) {
  __shared__ int part[256];
  int t = threadIdx.x;
  int chunk = (N + 255) >> 8;
  int base = t * chunk;
  int lim = N - base; if (lim > chunk) lim = chunk; if (lim < 0) lim = 0;
  int s = 0;
  for (int i = 0; i < lim; ++i) s += deg[base + i];
  part[t] = s;
  __syncthreads();
  for (int off = 1; off < 256; off <<= 1) {
    int v = part[t];
    int u = (t >= off) ? part[t - off] : 0;
    __syncthreads();
    part[t] = v + u;
    __syncthreads();
  }
  int run = (t == 0) ? 0 : part[t - 1];
  for (int i = 0; i < lim; ++i) {
    offs[base + i] = run;
    cursor[base + i] = run;
    run += deg[base + i];
  }
  if (t == 255) offs[N] = run;
}

__global__ __launch_bounds__(256) void k_scatter(const int* __restrict__ edst,
                                                 int* __restrict__ cursor,
                                                 int* __restrict__ eidx, int E) {
  int e = blockIdx.x * 256 + threadIdx.x;
  if (e < E) {
    int d = edst[e];
    int pos = atomicAdd(&cursor[d], 1);
    eidx[pos] = e;
  }
}

// ---------------- linear_up: x[n][d][q] = sum_c nf[n][c][d]*Wup[l(d)][c][q] ----------------
__global__ __launch_bounds__(256) void k_linear_up(
    const float* __restrict__ nf, const float* __restrict__ Wup,
    float* __restrict__ x, int N) {
  __shared__ float sW[3 * CC * CC];
  __shared__ float snf[8 * CD];
  for (int i = threadIdx.x; i < 3 * CC * CC; i += 256) sW[i] = Wup[i];
  int node0 = blockIdx.x * 8;
  int cnt = N - node0; if (cnt > 8) cnt = 8;
  const float* src = nf + (size_t)node0 * CD;
  for (int i = threadIdx.x; i < cnt * CD; i += 256) snf[i] = src[i];
  __syncthreads();
  float* dst = x + (size_t)node0 * CD;
  for (int o = threadIdx.x; o < cnt * CD; o += 256) {
    int nl = o / CD, rem = o - nl * CD;
    int d = rem >> 5, q = rem & 31;
    int l = blk_of(d);
    const float* wcol = sW + l * (CC * CC) + q;
    const float* frow = snf + nl * CD + d;
    float acc = 0.f;
#pragma unroll
    for (int c = 0; c < CC; ++c) acc += frow[c * DD] * wcol[c * CC];
    dst[o] = acc;
  }
}

// ---------------- radial MLP: w[e][c] = (silu(silu(ef@W1)@W2)@W3)[c] * cutoff[e] ----------------
__global__ __launch_bounds__(256) void k_mlp(
    const float* __restrict__ ef, const float* __restrict__ cut,
    const float* __restrict__ W1, const float* __restrict__ W2,
    const float* __restrict__ W3, float* __restrict__ w, int E) {
  __shared__ float sW1[BB * HH];
  __shared__ float sW2[HH * HH];
  __shared__ float sW3[HH * CC];
  __shared__ float sh1[8][HH];
  __shared__ float sh2[8][HH];
  __shared__ float sef[64];
  for (int i = threadIdx.x; i < BB * HH; i += 256) sW1[i] = W1[i];
  for (int i = threadIdx.x; i < HH * HH; i += 256) sW2[i] = W2[i];
  for (int i = threadIdx.x; i < HH * CC; i += 256) sW3[i] = W3[i];
  int g = threadIdx.x >> 5;
  int lane = threadIdx.x & 31;
  int nbatch = E >> 3;
  for (int batch = blockIdx.x; batch < nbatch; batch += gridDim.x) {
    __syncthreads();
    int t = threadIdx.x;
    if (t < 64) sef[t] = ef[(size_t)batch * 64 + t];
    __syncthreads();
#pragma unroll
    for (int half = 0; half < 2; ++half) {
      int q = lane + half * 32;
      float acc = 0.f;
#pragma unroll
      for (int k = 0; k < BB; ++k) acc += sef[g * 8 + k] * sW1[k * HH + q];
      sh1[g][q] = silu_f(acc);
    }
    __syncthreads();
#pragma unroll
    for (int half = 0; half < 2; ++half) {
      int q = lane + half * 32;
      float acc = 0.f;
#pragma unroll
      for (int k = 0; k < HH; ++k) acc += sh1[g][k] * sW2[k * HH + q];
      sh2[g][q] = silu_f(acc);
    }
    __syncthreads();
    float wc = 0.f;
#pragma unroll
    for (int k = 0; k < HH; ++k) wc += sh2[g][k] * sW3[k * CC + lane];
    int e = batch * 8 + g;
    w[(size_t)e * CC + lane] = wc * cut[e];
  }
}

// ---------------- gather: one wave per node, halves split even/odd edges ----------------
// P[c][i][j] = sum_e (w_ec * x[src_e][i][c]) * sh_e[j];  m[c][k] = sum_ij P*CG[i][j][k]
__global__ __launch_bounds__(256) void k_gather(
    const float* __restrict__ x, const float* __restrict__ w,
    const float* __restrict__ esh, const float* __restrict__ CG,
    const int* __restrict__ offs, const int* __restrict__ eidx,
    const int* __restrict__ esrc, float* __restrict__ mpre, int N) {
  int wid = (blockIdx.x * 256 + threadIdx.x) >> 6;  // node id
  if (wid >= N) return;
  int lane = threadIdx.x & 63;
  int h = lane >> 5, c = lane & 31;
  int beg = offs[wid], end = offs[wid + 1];
  float P[81];
#pragma unroll
  for (int i = 0; i < 81; ++i) P[i] = 0.f;
  for (int p0 = beg; p0 < end; p0 += 2) {
    int p = p0 + h;
    bool ok = p < end;
    int pp = ok ? p : p0;
    int e = eidx[pp];
    int s = esrc[e];
    float wc = ok ? w[(size_t)e * CC + c] : 0.f;
    const float* shp = esh + (size_t)e * DD;
    float sh[DD];
#pragma unroll
    for (int j = 0; j < DD; ++j) sh[j] = shp[j];
    const float* xp = x + (size_t)s * CD + c;
    float xs[DD];
#pragma unroll
    for (int i = 0; i < DD; ++i) xs[i] = xp[i * 32];
#pragma unroll
    for (int i = 0; i < DD; ++i) {
      float t = wc * xs[i];
#pragma unroll
      for (int j = 0; j < DD; ++j) P[i * DD + j] += t * sh[j];
    }
  }
  float m[DD];
#pragma unroll
  for (int k = 0; k < DD; ++k) m[k] = 0.f;
#pragma unroll
  for (int i = 0; i < DD; ++i) {
#pragma unroll
    for (int j = 0; j < DD; ++j) {
      float p = P[i * DD + j];
#pragma unroll
      for (int k = 0; k < DD; ++k) m[k] += p * CG[i * 81 + j * DD + k];
    }
  }
#pragma unroll
  for (int k = 0; k < DD; ++k) m[k] += __shfl_xor(m[k], 32);
  if (h == 0) {
    float* mp = mpre + (size_t)wid * CD + c;
#pragma unroll
    for (int k = 0; k < DD; ++k) mp[k * 32] = m[k];
  }
}

// ---------------- output linear + self-connection ----------------
__global__ __launch_bounds__(256) void k_out(
    const float* __restrict__ attrs, const float* __restrict__ Wlin,
    const float* __restrict__ Wsc,
    float* __restrict__ out1, float* __restrict__ out2, int N) {
  __shared__ float sWlin[3 * CC * CC];
  __shared__ float sWsc[ZZ * 3 * CC * CC];
  __shared__ float sWn[3 * CC * CC];
  __shared__ float smp[DD * 33];
  __shared__ float smi[DD * 33];
  for (int i = threadIdx.x; i < 3 * CC * CC; i += 256) sWlin[i] = Wlin[i];
  for (int i = threadIdx.x; i < ZZ * 3 * CC * CC; i += 256) sWsc[i] = Wsc[i];
  for (int n = blockIdx.x; n < N; n += gridDim.x) {
    __syncthreads();
    const float* mg = out2 + (size_t)n * CD;
    for (int j = threadIdx.x; j < CD; j += 256) {
      int dd = j >> 5, ccc = j & 31;
      smp[dd * 33 + ccc] = mg[j];
    }
    __syncthreads();
    for (int o = threadIdx.x; o < CD; o += 256) {
      int q = o / 9, d = o - q * 9;
      int l = blk_of(d);
      float acc = 0.f;
#pragma unroll
      for (int c = 0; c < CC; ++c) acc += smp[d * 33 + c] * sWlin[l * 1024 + c * 32 + q];
      acc *= (1.0f / 16.0f);
      smi[d * 33 + q] = acc;
      out1[(size_t)n * CD + o] = acc;
    }
    float a0 = attrs[n * 4 + 0], a1 = attrs[n * 4 + 1];
    float a2 = attrs[n * 4 + 2], a3 = attrs[n * 4 + 3];
    for (int o = threadIdx.x; o < 3 * CC * CC; o += 256) {
      sWn[o] = a0 * sWsc[o] + a1 * sWsc[3072 + o] + a2 * sWsc[2 * 3072 + o] + a3 * sWsc[3 * 3072 + o];
    }
    __syncthreads();
    for (int o = threadIdx.x; o < CD; o += 256) {
      int q = o / 9, d = o - q * 9;
      int l = blk_of(d);
      float acc = 0.f;
#pragma unroll
      for (int c = 0; c < CC; ++c) acc += smi[d * 33 + c] * sWn[l * 1024 + c * 32 + q];
      out2[(size_t)n * CD + o] = acc;
    }
  }
}

extern "C" void kernel_launch(void* const* d_in, const int* in_sizes, int n_in,
                              void* d_out, int out_size, void* d_ws, size_t ws_size,
                              hipStream_t stream) {
  const float* nf    = (const float*)d_in[0];
  const float* attrs = (const float*)d_in[1];
  const float* ef    = (const float*)d_in[2];
  const float* esh   = (const float*)d_in[3];
  const float* cutv  = (const float*)d_in[4];
  const float* Wup   = (const float*)d_in[5];
  const float* W1    = (const float*)d_in[6];
  const float* W2    = (const float*)d_in[7];
  const float* W3    = (const float*)d_in[8];
  const float* Wlin  = (const float*)d_in[9];
  const float* Wsc   = (const float*)d_in[10];
  const float* CG    = (const float*)d_in[11];
  const int* esrc    = (const int*)d_in[12];
  const int* edst    = (const int*)d_in[13];
  int N = in_sizes[0] / CD;
  int E = in_sizes[12];
  float* out1 = (float*)d_out;
  float* out2 = out1 + (size_t)N * CD;   // doubles as the m_pre accumulator

  // workspace layout
  float* x   = (float*)d_ws;                       // N*288 f32
  float* w   = x + (size_t)N * CD;                 // E*32 f32
  int* deg    = (int*)(w + (size_t)E * CC);        // N
  int* offs   = deg + N;                           // N+1
  int* cursor = offs + N + 1;                      // N
  int* eidx   = cursor + N;                        // E

  k_zero<<<(N + 255) / 256, 256, 0, stream>>>((float*)deg, N);
  k_hist<<<(E + 255) / 256, 256, 0, stream>>>(edst, deg, E);
  k_scan<<<1, 256, 0, stream>>>(deg, offs, cursor, N);
  k_scatter<<<(E + 255) / 256, 256, 0, stream>>>(edst, cursor, eidx, E);
  k_linear_up<<<(N + 7) / 8, 256, 0, stream>>>(nf, Wup, x, N);
  k_mlp<<<2048, 256, 0, stream>>>(ef, cutv, W1, W2, W3, w, E);
  k_gather<<<(N + 3) / 4, 256, 0, stream>>>(x, w, esh, CG, offs, eidx, esrc, out2, N);
  k_out<<<2048, 256, 0, stream>>>(attrs, Wlin, Wsc, out1, out2, N);
}